// Round 18
// baseline (95.927 us; speedup 1.0000x reference)
//
#include <hip/hip_runtime.h>
#include <hip/hip_bf16.h>

#define B_ 2
#define C_ 128
#define N_ 4096
#define NH_ 4
#define HD_ 32
#define GROUPS_ 32
#define EPS_ 1e-5f
// (1/sqrt(32)) * log2(e): QK^T computed directly in log2 domain
#define SCALE2_ 0.25503486f
#define NCH_ 4           // KV chunks
#define CHKV_ 1024       // KV rows per chunk
#define NT_ (CHKV_ / 64) // 64-row KV tiles per chunk

typedef __attribute__((ext_vector_type(2))) float f32x2;
typedef __attribute__((ext_vector_type(4))) float f32x4;
typedef __attribute__((ext_vector_type(8))) short s16x8;
typedef __attribute__((ext_vector_type(2))) unsigned int u32x2;
typedef __attribute__((ext_vector_type(4))) unsigned int u32x4;
typedef unsigned short u16;
typedef unsigned int u32;

static __device__ __forceinline__ u32 cvtpk_bf16(float lo, float hi) {
  u32 r;
  asm("v_cvt_pk_bf16_f32 %0, %1, %2" : "=v"(r) : "v"(lo), "v"(hi));
  return r;
}
// raw v_exp_f32: inputs bounded (|S*log2e| < ~12), no denorm fixup needed
static __device__ __forceinline__ float fexp2(float x) {
  float r;
  asm("v_exp_f32 %0, %1" : "=v"(r) : "v"(x));
  return r;
}
// unpack u32 holding 2 bf16 -> 2 f32 (low halfword = first element)
static __device__ __forceinline__ float bflo(u32 w) { return __uint_as_float(w << 16); }
static __device__ __forceinline__ float bfhi(u32 w) { return __uint_as_float(w & 0xffff0000u); }
static __device__ __forceinline__ u16 f2bf16(float f) { return (u16)cvtpk_bf16(f, f); }

// ---------------- GroupNorm -> bf16 xn. One 1024-thread block per (b, group) -
__global__ __launch_bounds__(1024) void k_groupnorm(
    const float* __restrict__ x, const float* __restrict__ gw,
    const float* __restrict__ gb, u16* __restrict__ xn) {
  const int blk = blockIdx.x;            // b*GROUPS + g
  const int tid = threadIdx.x;
  const size_t base = (size_t)blk * (4 * N_);   // contiguous 16384 elems
  const f32x4* x4 = (const f32x4*)(x + base);
  float s = 0.f, ss = 0.f;
  #pragma unroll
  for (int i = tid; i < 4096; i += 1024) {
    f32x4 v = x4[i];
    s  += v.x + v.y + v.z + v.w;
    ss += v.x*v.x + v.y*v.y + v.z*v.z + v.w*v.w;
  }
  for (int off = 32; off; off >>= 1) {
    s  += __shfl_down(s, off);
    ss += __shfl_down(ss, off);
  }
  __shared__ float red[2][16];
  __shared__ float mv[2];
  const int wid = tid >> 6;
  if ((tid & 63) == 0) { red[0][wid] = s; red[1][wid] = ss; }
  __syncthreads();
  if (tid == 0) {
    float S = 0.f, Q = 0.f;
    #pragma unroll
    for (int i = 0; i < 16; ++i) { S += red[0][i]; Q += red[1][i]; }
    float mu  = S * (1.f/16384.f);
    float var = Q * (1.f/16384.f) - mu*mu;
    mv[0] = mu; mv[1] = rsqrtf(var + EPS_);
  }
  __syncthreads();
  const float mu = mv[0], rs = mv[1];
  const int gi = blk & (GROUPS_ - 1);
  u32x2* xn2 = (u32x2*)(xn + base);
  #pragma unroll
  for (int i = tid; i < 4096; i += 1024) {
    const int c = gi*4 + (i >> 10);
    const float a  = gw[c] * rs;
    const float b2 = gb[c] - mu * a;
    f32x4 v = x4[i];
    f32x4 r = v * a + b2;
    u32x2 p = { cvtpk_bf16(r.x, r.y), cvtpk_bf16(r.z, r.w) };
    xn2[i] = p;
  }
}

// ---------------- QKV GEMM -> bf16; K rows written TRANSPOSED to Kt ----------
// Grid (8, 48, B): n-block 512, o-block 8 -> 768 blocks (3/CU, balanced).
__global__ __launch_bounds__(256) void k_gemm_qkv(
    const u16* __restrict__ xn, const float* __restrict__ w,
    const float* __restrict__ bias, u16* __restrict__ qkvb,
    u16* __restrict__ Kt) {
  const int tid = threadIdx.x;
  const int n0 = blockIdx.x * 512 + tid * 2;
  const int o0 = blockIdx.y * 8;
  const int b  = blockIdx.z;
  const u16* xb = xn + (size_t)b * C_ * N_;
  const float* wp = w + (size_t)o0 * C_;
  float ax[8] = {0,0,0,0,0,0,0,0};
  float ay[8] = {0,0,0,0,0,0,0,0};
  #pragma unroll 4
  for (int c = 0; c < C_; ++c) {
    const u32 wv = *(const u32*)(xb + (size_t)c * N_ + n0);
    const float x0 = bflo(wv), x1 = bfhi(wv);
    #pragma unroll
    for (int i = 0; i < 8; ++i) {
      const float wi = wp[(size_t)i * C_ + c];
      ax[i] += x0 * wi;
      ay[i] += x1 * wi;
    }
  }
  #pragma unroll
  for (int i = 0; i < 8; ++i) {
    const float bi = bias[o0 + i];
    ax[i] += bi; ay[i] += bi;
  }
  if (o0 < 128) {            // Q: scale and write rows
    u16* op = qkvb + ((size_t)b * 384 + o0) * N_ + n0;
    #pragma unroll
    for (int i = 0; i < 8; ++i)
      *(u32*)(op + (size_t)i * N_) = cvtpk_bf16(ax[i] * SCALE2_, ay[i] * SCALE2_);
  } else if (o0 < 256) {     // K: transposed into Kt[b][h][m][d]
    const int h  = (o0 - 128) >> 5;
    const int d8 = (o0 - 128) & 31;
    u16* kb = Kt + (size_t)(b * NH_ + h) * N_ * HD_ + d8;
    u32x4 pk0 = { cvtpk_bf16(ax[0], ax[1]), cvtpk_bf16(ax[2], ax[3]),
                  cvtpk_bf16(ax[4], ax[5]), cvtpk_bf16(ax[6], ax[7]) };
    u32x4 pk1 = { cvtpk_bf16(ay[0], ay[1]), cvtpk_bf16(ay[2], ay[3]),
                  cvtpk_bf16(ay[4], ay[5]), cvtpk_bf16(ay[6], ay[7]) };
    *(u32x4*)(kb + (size_t)n0 * HD_)       = pk0;
    *(u32x4*)(kb + (size_t)(n0 + 1) * HD_) = pk1;
  } else {                   // V: write rows
    u16* op = qkvb + ((size_t)b * 384 + o0) * N_ + n0;
    #pragma unroll
    for (int i = 0; i < 8; ++i)
      *(u32*)(op + (size_t)i * N_) = cvtpk_bf16(ax[i], ay[i]);
  }
}

// ---------------- Flash attention: 4 q-tiles/wave, LDS-staged K/V ------------
// (R16 config; launched TWICE this round as a duplicate-launch timing probe --
// pure function of (qkvb,Kt) so the second launch is bit-identical.)
#define QTILE_STEP(qf, oa0, oa1, oL)                                           \
  {                                                                            \
    f32x4 s0 = __builtin_amdgcn_mfma_f32_16x16x32_bf16(ck0, qf, z, 0, 0, 0);   \
    f32x4 s1 = __builtin_amdgcn_mfma_f32_16x16x32_bf16(ck1, qf, z, 0, 0, 0);   \
    f32x4 s2 = __builtin_amdgcn_mfma_f32_16x16x32_bf16(ck2, qf, z, 0, 0, 0);   \
    f32x4 s3 = __builtin_amdgcn_mfma_f32_16x16x32_bf16(ck3, qf, z, 0, 0, 0);   \
    float p0 = fexp2(s0.x), p1 = fexp2(s0.y), p2 = fexp2(s0.z), p3 = fexp2(s0.w); \
    float p4 = fexp2(s1.x), p5 = fexp2(s1.y), p6 = fexp2(s1.z), p7 = fexp2(s1.w); \
    float p8 = fexp2(s2.x), p9 = fexp2(s2.y), pa_ = fexp2(s2.z), pb_ = fexp2(s2.w); \
    float pc_ = fexp2(s3.x), pd_ = fexp2(s3.y), pe_ = fexp2(s3.z), pf_ = fexp2(s3.w); \
    union { u32x4 u; s16x8 s; } pkA, pkB;                                      \
    pkA.u.x = cvtpk_bf16(p0, p1);   pkA.u.y = cvtpk_bf16(p2, p3);              \
    pkA.u.z = cvtpk_bf16(p4, p5);   pkA.u.w = cvtpk_bf16(p6, p7);              \
    pkB.u.x = cvtpk_bf16(p8, p9);   pkB.u.y = cvtpk_bf16(pa_, pb_);            \
    pkB.u.z = cvtpk_bf16(pc_, pd_); pkB.u.w = cvtpk_bf16(pe_, pf_);            \
    oa0 = __builtin_amdgcn_mfma_f32_16x16x32_bf16(pkA.s, cv0, oa0, 0, 0, 0);   \
    oa1 = __builtin_amdgcn_mfma_f32_16x16x32_bf16(pkA.s, cv1, oa1, 0, 0, 0);   \
    oL  = __builtin_amdgcn_mfma_f32_16x16x32_bf16(pkA.s, onesB, oL, 0, 0, 0);  \
    oa0 = __builtin_amdgcn_mfma_f32_16x16x32_bf16(pkB.s, cv2, oa0, 0, 0, 0);   \
    oa1 = __builtin_amdgcn_mfma_f32_16x16x32_bf16(pkB.s, cv3, oa1, 0, 0, 0);   \
    oL  = __builtin_amdgcn_mfma_f32_16x16x32_bf16(pkB.s, onesB, oL, 0, 0, 0);  \
  }

__global__ __launch_bounds__(256) void k_attn(
    const u16* __restrict__ qkvb, const u16* __restrict__ Kt,
    u16* __restrict__ Opart, float* __restrict__ Lpart) {
  __shared__ u16 Kl[64 * 32];      // [m][d] 4KB, 16B-slot swizzled
  __shared__ u16 Vl[32 * 72];      // [d][m padded] 4.5KB
  const int b = blockIdx.z, h = blockIdx.y;
  const int qt = blockIdx.x & 15, ch = blockIdx.x >> 4;
  const int tid = threadIdx.x;
  const int wid = tid >> 6, lane = tid & 63;
  const int g = lane >> 4, lq = lane & 15;
  const int q0 = qt * 256 + wid * 16;        // tiles at +0, +64, +128, +192
  const int kv0 = ch * CHKV_;

  // Q B-frags (bf16, pre-scaled): one-time scattered u16 loads
  const u16* qb = qkvb + ((size_t)b * 384 + h * HD_) * N_;
  s16x8 qfA, qfB, qfC, qfD;
  #pragma unroll
  for (int j = 0; j < 8; ++j) {
    const u16* qr = qb + (size_t)(8*g + j) * N_ + q0 + lq;
    qfA[j] = (short)qr[0];
    qfB[j] = (short)qr[64];
    qfC[j] = (short)qr[128];
    qfD[j] = (short)qr[192];
  }

  const u16* ktb = Kt + (size_t)(b * NH_ + h) * N_ * HD_;            // [m][d]
  const u16* vbb = qkvb + ((size_t)b * 384 + 256 + h * HD_) * N_;    // [d][m]
  const int pi = ((lq >> 2) << 3) + (lq & 3);   // A-row -> K row permutation

  // staging (coalesced): K = one s16x8/thread, V = one s16x8/thread
  const u16* kst = ktb + (size_t)kv0 * HD_ + tid * 8;        // + tt*64*HD_
  const int vrow = tid >> 3;            // 0..31 (d)
  const int vcol = (tid & 7) * 8;       // 0..56 (m)
  const u16* vst = vbb + (size_t)vrow * N_ + kv0 + vcol;     // + tt*64
  u16* kdst = Kl + ((tid * 8) ^ (((tid >> 5) & 3) * 8));     // swizzled slot
  u16* vdst = Vl + vrow * 72 + vcol;

  // fragment LDS addresses (elements); K slots swizzled by x=(pi>>3)&3
  const int xsw  = (pi >> 3) & 3;
  const int slot = 8 * (g ^ xsw);
  const int ka0 = (pi)      * 32 + slot;
  const int ka1 = (pi + 4)  * 32 + slot;
  const int ka2 = (pi + 32) * 32 + slot;
  const int ka3 = (pi + 36) * 32 + slot;
  const int va0 = lq * 72 + 8*g;
  const int va1 = (lq + 16) * 72 + 8*g;

  const short one_bf = (short)0x3F80;   // bf16 1.0
  const s16x8 onesB = {one_bf, one_bf, one_bf, one_bf,
                       one_bf, one_bf, one_bf, one_bf};

  f32x4 oa0A = {0.f,0.f,0.f,0.f}, oa1A = oa0A, oLA = oa0A;
  f32x4 oa0B = oa0A, oa1B = oa0A, oLB = oa0A;
  f32x4 oa0C = oa0A, oa1C = oa0A, oLC = oa0A;
  f32x4 oa0D = oa0A, oa1D = oa0A, oLD = oa0A;

  // prologue: stage tile 0
  {
    s16x8 kr = *(const s16x8*)(kst);
    s16x8 vr = *(const s16x8*)(vst);
    *(s16x8*)(kdst) = kr;
    *(s16x8*)(vdst) = vr;
  }
  __syncthreads();

  for (int tt = 0; tt < NT_; ++tt) {
    // issue next-tile loads early (clamped on last iter; rewrite is harmless)
    const int tn = (tt + 1 < NT_) ? (tt + 1) : (NT_ - 1);
    s16x8 kr = *(const s16x8*)(kst + (size_t)tn * 64 * HD_);
    s16x8 vr = *(const s16x8*)(vst + (size_t)tn * 64);

    // fragments from LDS (shared by all four q-tiles)
    const s16x8 ck0 = *(const s16x8*)(Kl + ka0);
    const s16x8 ck1 = *(const s16x8*)(Kl + ka1);
    const s16x8 ck2 = *(const s16x8*)(Kl + ka2);
    const s16x8 ck3 = *(const s16x8*)(Kl + ka3);
    const s16x8 cv0 = *(const s16x8*)(Vl + va0);
    const s16x8 cv1 = *(const s16x8*)(Vl + va1);
    const s16x8 cv2 = *(const s16x8*)(Vl + va0 + 32);
    const s16x8 cv3 = *(const s16x8*)(Vl + va1 + 32);

    const f32x4 z = {0.f,0.f,0.f,0.f};
    QTILE_STEP(qfA, oa0A, oa1A, oLA)
    QTILE_STEP(qfB, oa0B, oa1B, oLB)
    QTILE_STEP(qfC, oa0C, oa1C, oLC)
    QTILE_STEP(qfD, oa0D, oa1D, oLD)

    __syncthreads();                 // all reads of Kl/Vl done
    *(s16x8*)(kdst) = kr;            // overwrite with next tile
    *(s16x8*)(vdst) = vr;
    __syncthreads();                 // next tile visible
  }

  // partial store (bf16): Opart[ch][b][h][q][d], Lpart[ch][b][h][q]
  const int bh = b * NH_ + h;
  u16* opb = Opart + ((size_t)ch * (B_ * NH_) + bh) * ((size_t)N_ * HD_);
  #pragma unroll
  for (int r = 0; r < 4; ++r) {
    const int qrow = q0 + g*4 + r;
    opb[(size_t)qrow * HD_ + lq]              = f2bf16(oa0A[r]);
    opb[(size_t)qrow * HD_ + lq + 16]         = f2bf16(oa1A[r]);
    opb[(size_t)(qrow + 64) * HD_ + lq]       = f2bf16(oa0B[r]);
    opb[(size_t)(qrow + 64) * HD_ + lq + 16]  = f2bf16(oa1B[r]);
    opb[(size_t)(qrow + 128) * HD_ + lq]      = f2bf16(oa0C[r]);
    opb[(size_t)(qrow + 128) * HD_ + lq + 16] = f2bf16(oa1C[r]);
    opb[(size_t)(qrow + 192) * HD_ + lq]      = f2bf16(oa0D[r]);
    opb[(size_t)(qrow + 192) * HD_ + lq + 16] = f2bf16(oa1D[r]);
  }
  if (lq == 0) {
    float* lp = Lpart + ((size_t)ch * (B_ * NH_) + bh) * N_ + q0 + g*4;
    lp[0]   = oLA[0]; lp[1]   = oLA[1]; lp[2]   = oLA[2]; lp[3]   = oLA[3];
    lp[64]  = oLB[0]; lp[65]  = oLB[1]; lp[66]  = oLB[2]; lp[67]  = oLB[3];
    lp[128] = oLC[0]; lp[129] = oLC[1]; lp[130] = oLC[2]; lp[131] = oLC[3];
    lp[192] = oLD[0]; lp[193] = oLD[1]; lp[194] = oLD[2]; lp[195] = oLD[3];
  }
}

// ---------------- Fused combine + out GEMM + bias + residual -----------------
// Grid (32, 4, B): block = [128 n] x [32 o].
__global__ __launch_bounds__(256) void k_out(
    const u16* __restrict__ Opart, const float* __restrict__ Lpart,
    const float* __restrict__ w, const float* __restrict__ bias,
    const float* __restrict__ x, float* __restrict__ y) {
  __shared__ u16 Ot[128][136];     // [c][n] bf16, +8 pad
  __shared__ float linv[NH_][128];
  const int t = threadIdx.x;
  const int n0 = blockIdx.x * 128;
  const int o0 = blockIdx.y * 32;
  const int b  = blockIdx.z;

  // per-head denominators for this n-range
  if (t < 128) {
    #pragma unroll
    for (int h = 0; h < NH_; ++h) {
      float s = 0.f;
      #pragma unroll
      for (int c = 0; c < NCH_; ++c)
        s += Lpart[((size_t)c * (B_ * NH_) + b * NH_ + h) * N_ + n0 + t];
      linv[h][t] = 1.0f / s;
    }
  }
  __syncthreads();

  // stage Ot[c=32h+d][n] = (sum_ch Opart[ch][bh][n0+n][d]) * linv[h][n]
  {
    const int dd = (t & 7) * 4;           // 0..28
    const int nb = t >> 3;                // 0..31
    #pragma unroll
    for (int h = 0; h < NH_; ++h) {
      const u16* ob = Opart + (size_t)(b * NH_ + h) * ((size_t)N_ * HD_)
                    + (size_t)n0 * HD_ + dd;
      #pragma unroll
      for (int p = 0; p < 4; ++p) {
        const int nn = p * 32 + nb;
        f32x4 a = {0.f,0.f,0.f,0.f};
        #pragma unroll
        for (int c = 0; c < NCH_; ++c) {
          const u32x2 ov = *(const u32x2*)(ob
              + (size_t)c * ((size_t)B_ * NH_ * N_ * HD_) + (size_t)nn * HD_);
          a.x += bflo(ov.x); a.y += bfhi(ov.x);
          a.z += bflo(ov.y); a.w += bfhi(ov.y);
        }
        const float iv = linv[h][nn];
        a *= iv;
        Ot[32*h + dd + 0][nn] = f2bf16(a.x);
        Ot[32*h + dd + 1][nn] = f2bf16(a.y);
        Ot[32*h + dd + 2][nn] = f2bf16(a.z);
        Ot[32*h + dd + 3][nn] = f2bf16(a.w);
      }
    }
  }
  __syncthreads();

  // GEMM: thread -> 4 o-rows x 4 n-cols
  const int n4  = (t & 31) * 4;             // 0..124
  const int orow = o0 + (t >> 5) * 4;       // 4 rows
  const float* wp = w + (size_t)orow * C_;
  f32x4 acc0 = {0.f,0.f,0.f,0.f}, acc1 = acc0, acc2 = acc0, acc3 = acc0;
  #pragma unroll 4
  for (int c = 0; c < C_; ++c) {
    const u32x2 ov = *(const u32x2*)(&Ot[c][n4]);
    const f32x4 xv = { bflo(ov.x), bfhi(ov.x), bflo(ov.y), bfhi(ov.y) };
    acc0 += xv * wp[c];
    acc1 += xv * wp[C_ + c];
    acc2 += xv * wp[2*C_ + c];
    acc3 += xv * wp[3*C_ + c];
  }
  const size_t yo = ((size_t)b * C_ + orow) * N_ + n0 + n4;
  const f32x4 xr0 = *(const f32x4*)(x + yo);
  const f32x4 xr1 = *(const f32x4*)(x + yo + N_);
  const f32x4 xr2 = *(const f32x4*)(x + yo + 2*N_);
  const f32x4 xr3 = *(const f32x4*)(x + yo + 3*N_);
  *(f32x4*)(y + yo)        = acc0 + bias[orow]     + xr0;
  *(f32x4*)(y + yo + N_)   = acc1 + bias[orow + 1] + xr1;
  *(f32x4*)(y + yo + 2*N_) = acc2 + bias[orow + 2] + xr2;
  *(f32x4*)(y + yo + 3*N_) = acc3 + bias[orow + 3] + xr3;
}

extern "C" void kernel_launch(void* const* d_in, const int* in_sizes, int n_in,
                              void* d_out, int out_size, void* d_ws, size_t ws_size,
                              hipStream_t stream) {
  const float* x     = (const float*)d_in[0];
  const float* gn_w  = (const float*)d_in[1];
  const float* gn_b  = (const float*)d_in[2];
  const float* qkv_w = (const float*)d_in[3];
  const float* qkv_b = (const float*)d_in[4];
  const float* out_w = (const float*)d_in[5];
  const float* out_b = (const float*)d_in[6];
  float* y = (float*)d_out;

  // ws layout (float offsets):
  //   xn    bf16: [0, 524288)            2 MB
  //   qkvb  bf16: [524288, 2097152)      6 MB  (Q scaled | unused | V)
  //   Kt    bf16: [2097152, 2621440)     2 MB
  //   Opart bf16: [2621440, 4718592)     8 MB  (4 chunks x [b][h][4096][32])
  //   Lpart f32 : [4718592, 4849664)   0.5 MB
  float* ws  = (float*)d_ws;
  u16*   xn   = (u16*)ws;
  u16*   qkvb = (u16*)(ws + 524288);
  u16*   Kt   = (u16*)(ws + 2097152);
  u16*   Opart = (u16*)(ws + 2621440);
  float* Lpart = ws + 4718592;

  k_groupnorm<<<dim3(B_ * GROUPS_), 1024, 0, stream>>>(x, gn_w, gn_b, xn);
  k_gemm_qkv <<<dim3(8, 48, B_),    256, 0, stream>>>(xn, qkv_w, qkv_b, qkvb, Kt);
  // duplicate-launch timing probe: k_attn is a pure function of (qkvb, Kt);
  // second launch is bit-identical. dur_us delta vs R16 == T_attn + 1 gap.
  k_attn     <<<dim3(16 * NCH_, NH_, B_), 256, 0, stream>>>(qkvb, Kt, Opart, Lpart);
  k_attn     <<<dim3(16 * NCH_, NH_, B_), 256, 0, stream>>>(qkvb, Kt, Opart, Lpart);
  k_out      <<<dim3(32, 4, B_),    256, 0, stream>>>(Opart, Lpart, out_w, out_b, x, y);
}

// Round 21
// 81.835 us; speedup vs baseline: 1.1722x; 1.1722x over previous
//
#include <hip/hip_runtime.h>
#include <hip/hip_bf16.h>

#define B_ 2
#define C_ 128
#define N_ 4096
#define NH_ 4
#define HD_ 32
#define GROUPS_ 32
#define EPS_ 1e-5f
// (1/sqrt(32)) * log2(e): QK^T computed directly in log2 domain
#define SCALE2_ 0.25503486f
#define NCH_ 4           // KV chunks
#define CHKV_ 1024       // KV rows per chunk
#define NT_ (CHKV_ / 64) // 64-row KV tiles per chunk

typedef __attribute__((ext_vector_type(2))) float f32x2;
typedef __attribute__((ext_vector_type(4))) float f32x4;
typedef __attribute__((ext_vector_type(8))) short s16x8;
typedef __attribute__((ext_vector_type(2))) unsigned int u32x2;
typedef __attribute__((ext_vector_type(4))) unsigned int u32x4;
typedef unsigned short u16;
typedef unsigned int u32;

static __device__ __forceinline__ u32 cvtpk_bf16(float lo, float hi) {
  u32 r;
  asm("v_cvt_pk_bf16_f32 %0, %1, %2" : "=v"(r) : "v"(lo), "v"(hi));
  return r;
}
// Full-rate exp2 (R18: v_exp_f32 is CU-shared quarter-rate => 27us floor on
// 134M exps; this 7-op VALU sequence runs at 32 lanes/cyc/SIMD instead).
// k=rndne(x), f=x-k in [-.5,.5], deg-3 poly (rel err ~8e-4 << bf16 rounding),
// scale by 2^k via v_ldexp_f32.
static __device__ __forceinline__ float fexp2(float x) {
  const float k = __builtin_rintf(x);
  const float f = x - k;
  float p = fmaf(f, 0.05550411f, 0.24022651f);
  p = fmaf(f, p, 0.69314718f);
  p = fmaf(f, p, 1.0f);
  return __builtin_amdgcn_ldexpf(p, (int)k);
}
// unpack u32 holding 2 bf16 -> 2 f32 (low halfword = first element)
static __device__ __forceinline__ float bflo(u32 w) { return __uint_as_float(w << 16); }
static __device__ __forceinline__ float bfhi(u32 w) { return __uint_as_float(w & 0xffff0000u); }
static __device__ __forceinline__ u16 f2bf16(float f) { return (u16)cvtpk_bf16(f, f); }

// ---------------- GroupNorm -> bf16 xn. One 1024-thread block per (b, group) -
__global__ __launch_bounds__(1024) void k_groupnorm(
    const float* __restrict__ x, const float* __restrict__ gw,
    const float* __restrict__ gb, u16* __restrict__ xn) {
  const int blk = blockIdx.x;            // b*GROUPS + g
  const int tid = threadIdx.x;
  const size_t base = (size_t)blk * (4 * N_);   // contiguous 16384 elems
  const f32x4* x4 = (const f32x4*)(x + base);
  float s = 0.f, ss = 0.f;
  #pragma unroll
  for (int i = tid; i < 4096; i += 1024) {
    f32x4 v = x4[i];
    s  += v.x + v.y + v.z + v.w;
    ss += v.x*v.x + v.y*v.y + v.z*v.z + v.w*v.w;
  }
  for (int off = 32; off; off >>= 1) {
    s  += __shfl_down(s, off);
    ss += __shfl_down(ss, off);
  }
  __shared__ float red[2][16];
  __shared__ float mv[2];
  const int wid = tid >> 6;
  if ((tid & 63) == 0) { red[0][wid] = s; red[1][wid] = ss; }
  __syncthreads();
  if (tid == 0) {
    float S = 0.f, Q = 0.f;
    #pragma unroll
    for (int i = 0; i < 16; ++i) { S += red[0][i]; Q += red[1][i]; }
    float mu  = S * (1.f/16384.f);
    float var = Q * (1.f/16384.f) - mu*mu;
    mv[0] = mu; mv[1] = rsqrtf(var + EPS_);
  }
  __syncthreads();
  const float mu = mv[0], rs = mv[1];
  const int gi = blk & (GROUPS_ - 1);
  u32x2* xn2 = (u32x2*)(xn + base);
  #pragma unroll
  for (int i = tid; i < 4096; i += 1024) {
    const int c = gi*4 + (i >> 10);
    const float a  = gw[c] * rs;
    const float b2 = gb[c] - mu * a;
    f32x4 v = x4[i];
    f32x4 r = v * a + b2;
    u32x2 p = { cvtpk_bf16(r.x, r.y), cvtpk_bf16(r.z, r.w) };
    xn2[i] = p;
  }
}

// ---------------- QKV GEMM -> bf16; K rows written TRANSPOSED to Kt ----------
// Grid (8, 48, B): n-block 512, o-block 8 -> 768 blocks (3/CU, balanced).
__global__ __launch_bounds__(256) void k_gemm_qkv(
    const u16* __restrict__ xn, const float* __restrict__ w,
    const float* __restrict__ bias, u16* __restrict__ qkvb,
    u16* __restrict__ Kt) {
  const int tid = threadIdx.x;
  const int n0 = blockIdx.x * 512 + tid * 2;
  const int o0 = blockIdx.y * 8;
  const int b  = blockIdx.z;
  const u16* xb = xn + (size_t)b * C_ * N_;
  const float* wp = w + (size_t)o0 * C_;
  float ax[8] = {0,0,0,0,0,0,0,0};
  float ay[8] = {0,0,0,0,0,0,0,0};
  #pragma unroll 4
  for (int c = 0; c < C_; ++c) {
    const u32 wv = *(const u32*)(xb + (size_t)c * N_ + n0);
    const float x0 = bflo(wv), x1 = bfhi(wv);
    #pragma unroll
    for (int i = 0; i < 8; ++i) {
      const float wi = wp[(size_t)i * C_ + c];
      ax[i] += x0 * wi;
      ay[i] += x1 * wi;
    }
  }
  #pragma unroll
  for (int i = 0; i < 8; ++i) {
    const float bi = bias[o0 + i];
    ax[i] += bi; ay[i] += bi;
  }
  if (o0 < 128) {            // Q: scale and write rows
    u16* op = qkvb + ((size_t)b * 384 + o0) * N_ + n0;
    #pragma unroll
    for (int i = 0; i < 8; ++i)
      *(u32*)(op + (size_t)i * N_) = cvtpk_bf16(ax[i] * SCALE2_, ay[i] * SCALE2_);
  } else if (o0 < 256) {     // K: transposed into Kt[b][h][m][d]
    const int h  = (o0 - 128) >> 5;
    const int d8 = (o0 - 128) & 31;
    u16* kb = Kt + (size_t)(b * NH_ + h) * N_ * HD_ + d8;
    u32x4 pk0 = { cvtpk_bf16(ax[0], ax[1]), cvtpk_bf16(ax[2], ax[3]),
                  cvtpk_bf16(ax[4], ax[5]), cvtpk_bf16(ax[6], ax[7]) };
    u32x4 pk1 = { cvtpk_bf16(ay[0], ay[1]), cvtpk_bf16(ay[2], ay[3]),
                  cvtpk_bf16(ay[4], ay[5]), cvtpk_bf16(ay[6], ay[7]) };
    *(u32x4*)(kb + (size_t)n0 * HD_)       = pk0;
    *(u32x4*)(kb + (size_t)(n0 + 1) * HD_) = pk1;
  } else {                   // V: write rows
    u16* op = qkvb + ((size_t)b * 384 + o0) * N_ + n0;
    #pragma unroll
    for (int i = 0; i < 8; ++i)
      *(u32*)(op + (size_t)i * N_) = cvtpk_bf16(ax[i], ay[i]);
  }
}

// ---------------- Flash attention: 4 q-tiles/wave, LDS-staged K/V ------------
#define QTILE_STEP(qf, oa0, oa1, oL)                                           \
  {                                                                            \
    f32x4 s0 = __builtin_amdgcn_mfma_f32_16x16x32_bf16(ck0, qf, z, 0, 0, 0);   \
    f32x4 s1 = __builtin_amdgcn_mfma_f32_16x16x32_bf16(ck1, qf, z, 0, 0, 0);   \
    f32x4 s2 = __builtin_amdgcn_mfma_f32_16x16x32_bf16(ck2, qf, z, 0, 0, 0);   \
    f32x4 s3 = __builtin_amdgcn_mfma_f32_16x16x32_bf16(ck3, qf, z, 0, 0, 0);   \
    float p0 = fexp2(s0.x), p1 = fexp2(s0.y), p2 = fexp2(s0.z), p3 = fexp2(s0.w); \
    float p4 = fexp2(s1.x), p5 = fexp2(s1.y), p6 = fexp2(s1.z), p7 = fexp2(s1.w); \
    float p8 = fexp2(s2.x), p9 = fexp2(s2.y), pa_ = fexp2(s2.z), pb_ = fexp2(s2.w); \
    float pc_ = fexp2(s3.x), pd_ = fexp2(s3.y), pe_ = fexp2(s3.z), pf_ = fexp2(s3.w); \
    union { u32x4 u; s16x8 s; } pkA, pkB;                                      \
    pkA.u.x = cvtpk_bf16(p0, p1);   pkA.u.y = cvtpk_bf16(p2, p3);              \
    pkA.u.z = cvtpk_bf16(p4, p5);   pkA.u.w = cvtpk_bf16(p6, p7);              \
    pkB.u.x = cvtpk_bf16(p8, p9);   pkB.u.y = cvtpk_bf16(pa_, pb_);            \
    pkB.u.z = cvtpk_bf16(pc_, pd_); pkB.u.w = cvtpk_bf16(pe_, pf_);            \
    oa0 = __builtin_amdgcn_mfma_f32_16x16x32_bf16(pkA.s, cv0, oa0, 0, 0, 0);   \
    oa1 = __builtin_amdgcn_mfma_f32_16x16x32_bf16(pkA.s, cv1, oa1, 0, 0, 0);   \
    oL  = __builtin_amdgcn_mfma_f32_16x16x32_bf16(pkA.s, onesB, oL, 0, 0, 0);  \
    oa0 = __builtin_amdgcn_mfma_f32_16x16x32_bf16(pkB.s, cv2, oa0, 0, 0, 0);   \
    oa1 = __builtin_amdgcn_mfma_f32_16x16x32_bf16(pkB.s, cv3, oa1, 0, 0, 0);   \
    oL  = __builtin_amdgcn_mfma_f32_16x16x32_bf16(pkB.s, onesB, oL, 0, 0, 0);  \
  }

__global__ __launch_bounds__(256) void k_attn(
    const u16* __restrict__ qkvb, const u16* __restrict__ Kt,
    u16* __restrict__ Opart, float* __restrict__ Lpart) {
  __shared__ u16 Kl[64 * 32];      // [m][d] 4KB, 16B-slot swizzled
  __shared__ u16 Vl[32 * 72];      // [d][m padded] 4.5KB
  const int b = blockIdx.z, h = blockIdx.y;
  const int qt = blockIdx.x & 15, ch = blockIdx.x >> 4;
  const int tid = threadIdx.x;
  const int wid = tid >> 6, lane = tid & 63;
  const int g = lane >> 4, lq = lane & 15;
  const int q0 = qt * 256 + wid * 16;        // tiles at +0, +64, +128, +192
  const int kv0 = ch * CHKV_;

  // Q B-frags (bf16, pre-scaled): one-time scattered u16 loads
  const u16* qb = qkvb + ((size_t)b * 384 + h * HD_) * N_;
  s16x8 qfA, qfB, qfC, qfD;
  #pragma unroll
  for (int j = 0; j < 8; ++j) {
    const u16* qr = qb + (size_t)(8*g + j) * N_ + q0 + lq;
    qfA[j] = (short)qr[0];
    qfB[j] = (short)qr[64];
    qfC[j] = (short)qr[128];
    qfD[j] = (short)qr[192];
  }

  const u16* ktb = Kt + (size_t)(b * NH_ + h) * N_ * HD_;            // [m][d]
  const u16* vbb = qkvb + ((size_t)b * 384 + 256 + h * HD_) * N_;    // [d][m]
  const int pi = ((lq >> 2) << 3) + (lq & 3);   // A-row -> K row permutation

  // staging (coalesced): K = one s16x8/thread, V = one s16x8/thread
  const u16* kst = ktb + (size_t)kv0 * HD_ + tid * 8;        // + tt*64*HD_
  const int vrow = tid >> 3;            // 0..31 (d)
  const int vcol = (tid & 7) * 8;       // 0..56 (m)
  const u16* vst = vbb + (size_t)vrow * N_ + kv0 + vcol;     // + tt*64
  u16* kdst = Kl + ((tid * 8) ^ (((tid >> 5) & 3) * 8));     // swizzled slot
  u16* vdst = Vl + vrow * 72 + vcol;

  // fragment LDS addresses (elements); K slots swizzled by x=(pi>>3)&3
  const int xsw  = (pi >> 3) & 3;
  const int slot = 8 * (g ^ xsw);
  const int ka0 = (pi)      * 32 + slot;
  const int ka1 = (pi + 4)  * 32 + slot;
  const int ka2 = (pi + 32) * 32 + slot;
  const int ka3 = (pi + 36) * 32 + slot;
  const int va0 = lq * 72 + 8*g;
  const int va1 = (lq + 16) * 72 + 8*g;

  const short one_bf = (short)0x3F80;   // bf16 1.0
  const s16x8 onesB = {one_bf, one_bf, one_bf, one_bf,
                       one_bf, one_bf, one_bf, one_bf};

  f32x4 oa0A = {0.f,0.f,0.f,0.f}, oa1A = oa0A, oLA = oa0A;
  f32x4 oa0B = oa0A, oa1B = oa0A, oLB = oa0A;
  f32x4 oa0C = oa0A, oa1C = oa0A, oLC = oa0A;
  f32x4 oa0D = oa0A, oa1D = oa0A, oLD = oa0A;

  // prologue: stage tile 0
  {
    s16x8 kr = *(const s16x8*)(kst);
    s16x8 vr = *(const s16x8*)(vst);
    *(s16x8*)(kdst) = kr;
    *(s16x8*)(vdst) = vr;
  }
  __syncthreads();

  for (int tt = 0; tt < NT_; ++tt) {
    // issue next-tile loads early (clamped on last iter; rewrite is harmless)
    const int tn = (tt + 1 < NT_) ? (tt + 1) : (NT_ - 1);
    s16x8 kr = *(const s16x8*)(kst + (size_t)tn * 64 * HD_);
    s16x8 vr = *(const s16x8*)(vst + (size_t)tn * 64);

    // fragments from LDS (shared by all four q-tiles)
    const s16x8 ck0 = *(const s16x8*)(Kl + ka0);
    const s16x8 ck1 = *(const s16x8*)(Kl + ka1);
    const s16x8 ck2 = *(const s16x8*)(Kl + ka2);
    const s16x8 ck3 = *(const s16x8*)(Kl + ka3);
    const s16x8 cv0 = *(const s16x8*)(Vl + va0);
    const s16x8 cv1 = *(const s16x8*)(Vl + va1);
    const s16x8 cv2 = *(const s16x8*)(Vl + va0 + 32);
    const s16x8 cv3 = *(const s16x8*)(Vl + va1 + 32);

    const f32x4 z = {0.f,0.f,0.f,0.f};
    QTILE_STEP(qfA, oa0A, oa1A, oLA)
    QTILE_STEP(qfB, oa0B, oa1B, oLB)
    QTILE_STEP(qfC, oa0C, oa1C, oLC)
    QTILE_STEP(qfD, oa0D, oa1D, oLD)

    __syncthreads();                 // all reads of Kl/Vl done
    *(s16x8*)(kdst) = kr;            // overwrite with next tile
    *(s16x8*)(vdst) = vr;
    __syncthreads();                 // next tile visible
  }

  // partial store (bf16): Opart[ch][b][h][q][d], Lpart[ch][b][h][q]
  const int bh = b * NH_ + h;
  u16* opb = Opart + ((size_t)ch * (B_ * NH_) + bh) * ((size_t)N_ * HD_);
  #pragma unroll
  for (int r = 0; r < 4; ++r) {
    const int qrow = q0 + g*4 + r;
    opb[(size_t)qrow * HD_ + lq]              = f2bf16(oa0A[r]);
    opb[(size_t)qrow * HD_ + lq + 16]         = f2bf16(oa1A[r]);
    opb[(size_t)(qrow + 64) * HD_ + lq]       = f2bf16(oa0B[r]);
    opb[(size_t)(qrow + 64) * HD_ + lq + 16]  = f2bf16(oa1B[r]);
    opb[(size_t)(qrow + 128) * HD_ + lq]      = f2bf16(oa0C[r]);
    opb[(size_t)(qrow + 128) * HD_ + lq + 16] = f2bf16(oa1C[r]);
    opb[(size_t)(qrow + 192) * HD_ + lq]      = f2bf16(oa0D[r]);
    opb[(size_t)(qrow + 192) * HD_ + lq + 16] = f2bf16(oa1D[r]);
  }
  if (lq == 0) {
    float* lp = Lpart + ((size_t)ch * (B_ * NH_) + bh) * N_ + q0 + g*4;
    lp[0]   = oLA[0]; lp[1]   = oLA[1]; lp[2]   = oLA[2]; lp[3]   = oLA[3];
    lp[64]  = oLB[0]; lp[65]  = oLB[1]; lp[66]  = oLB[2]; lp[67]  = oLB[3];
    lp[128] = oLC[0]; lp[129] = oLC[1]; lp[130] = oLC[2]; lp[131] = oLC[3];
    lp[192] = oLD[0]; lp[193] = oLD[1]; lp[194] = oLD[2]; lp[195] = oLD[3];
  }
}

// ---------------- Fused combine + out GEMM + bias + residual -----------------
// Grid (32, 4, B): block = [128 n] x [32 o].
__global__ __launch_bounds__(256) void k_out(
    const u16* __restrict__ Opart, const float* __restrict__ Lpart,
    const float* __restrict__ w, const float* __restrict__ bias,
    const float* __restrict__ x, float* __restrict__ y) {
  __shared__ u16 Ot[128][136];     // [c][n] bf16, +8 pad
  __shared__ float linv[NH_][128];
  const int t = threadIdx.x;
  const int n0 = blockIdx.x * 128;
  const int o0 = blockIdx.y * 32;
  const int b  = blockIdx.z;

  // per-head denominators for this n-range
  if (t < 128) {
    #pragma unroll
    for (int h = 0; h < NH_; ++h) {
      float s = 0.f;
      #pragma unroll
      for (int c = 0; c < NCH_; ++c)
        s += Lpart[((size_t)c * (B_ * NH_) + b * NH_ + h) * N_ + n0 + t];
      linv[h][t] = 1.0f / s;
    }
  }
  __syncthreads();

  // stage Ot[c=32h+d][n] = (sum_ch Opart[ch][bh][n0+n][d]) * linv[h][n]
  {
    const int dd = (t & 7) * 4;           // 0..28
    const int nb = t >> 3;                // 0..31
    #pragma unroll
    for (int h = 0; h < NH_; ++h) {
      const u16* ob = Opart + (size_t)(b * NH_ + h) * ((size_t)N_ * HD_)
                    + (size_t)n0 * HD_ + dd;
      #pragma unroll
      for (int p = 0; p < 4; ++p) {
        const int nn = p * 32 + nb;
        f32x4 a = {0.f,0.f,0.f,0.f};
        #pragma unroll
        for (int c = 0; c < NCH_; ++c) {
          const u32x2 ov = *(const u32x2*)(ob
              + (size_t)c * ((size_t)B_ * NH_ * N_ * HD_) + (size_t)nn * HD_);
          a.x += bflo(ov.x); a.y += bfhi(ov.x);
          a.z += bflo(ov.y); a.w += bfhi(ov.y);
        }
        const float iv = linv[h][nn];
        a *= iv;
        Ot[32*h + dd + 0][nn] = f2bf16(a.x);
        Ot[32*h + dd + 1][nn] = f2bf16(a.y);
        Ot[32*h + dd + 2][nn] = f2bf16(a.z);
        Ot[32*h + dd + 3][nn] = f2bf16(a.w);
      }
    }
  }
  __syncthreads();

  // GEMM: thread -> 4 o-rows x 4 n-cols
  const int n4  = (t & 31) * 4;             // 0..124
  const int orow = o0 + (t >> 5) * 4;       // 4 rows
  const float* wp = w + (size_t)orow * C_;
  f32x4 acc0 = {0.f,0.f,0.f,0.f}, acc1 = acc0, acc2 = acc0, acc3 = acc0;
  #pragma unroll 4
  for (int c = 0; c < C_; ++c) {
    const u32x2 ov = *(const u32x2*)(&Ot[c][n4]);
    const f32x4 xv = { bflo(ov.x), bfhi(ov.x), bflo(ov.y), bfhi(ov.y) };
    acc0 += xv * wp[c];
    acc1 += xv * wp[C_ + c];
    acc2 += xv * wp[2*C_ + c];
    acc3 += xv * wp[3*C_ + c];
  }
  const size_t yo = ((size_t)b * C_ + orow) * N_ + n0 + n4;
  const f32x4 xr0 = *(const f32x4*)(x + yo);
  const f32x4 xr1 = *(const f32x4*)(x + yo + N_);
  const f32x4 xr2 = *(const f32x4*)(x + yo + 2*N_);
  const f32x4 xr3 = *(const f32x4*)(x + yo + 3*N_);
  *(f32x4*)(y + yo)        = acc0 + bias[orow]     + xr0;
  *(f32x4*)(y + yo + N_)   = acc1 + bias[orow + 1] + xr1;
  *(f32x4*)(y + yo + 2*N_) = acc2 + bias[orow + 2] + xr2;
  *(f32x4*)(y + yo + 3*N_) = acc3 + bias[orow + 3] + xr3;
}

extern "C" void kernel_launch(void* const* d_in, const int* in_sizes, int n_in,
                              void* d_out, int out_size, void* d_ws, size_t ws_size,
                              hipStream_t stream) {
  const float* x     = (const float*)d_in[0];
  const float* gn_w  = (const float*)d_in[1];
  const float* gn_b  = (const float*)d_in[2];
  const float* qkv_w = (const float*)d_in[3];
  const float* qkv_b = (const float*)d_in[4];
  const float* out_w = (const float*)d_in[5];
  const float* out_b = (const float*)d_in[6];
  float* y = (float*)d_out;

  // ws layout (float offsets):
  //   xn    bf16: [0, 524288)            2 MB
  //   qkvb  bf16: [524288, 2097152)      6 MB  (Q scaled | unused | V)
  //   Kt    bf16: [2097152, 2621440)     2 MB
  //   Opart bf16: [2621440, 4718592)     8 MB  (4 chunks x [b][h][4096][32])
  //   Lpart f32 : [4718592, 4849664)   0.5 MB
  float* ws  = (float*)d_ws;
  u16*   xn   = (u16*)ws;
  u16*   qkvb = (u16*)(ws + 524288);
  u16*   Kt   = (u16*)(ws + 2097152);
  u16*   Opart = (u16*)(ws + 2621440);
  float* Lpart = ws + 4718592;

  k_groupnorm<<<dim3(B_ * GROUPS_), 1024, 0, stream>>>(x, gn_w, gn_b, xn);
  k_gemm_qkv <<<dim3(8, 48, B_),    256, 0, stream>>>(xn, qkv_w, qkv_b, qkvb, Kt);
  k_attn     <<<dim3(16 * NCH_, NH_, B_), 256, 0, stream>>>(qkvb, Kt, Opart, Lpart);
  k_out      <<<dim3(32, 4, B_),    256, 0, stream>>>(Opart, Lpart, out_w, out_b, x, y);
}

// Round 23
// 68.482 us; speedup vs baseline: 1.4008x; 1.1950x over previous
//
#include <hip/hip_runtime.h>
#include <hip/hip_bf16.h>

#define B_ 2
#define C_ 128
#define N_ 4096
#define NH_ 4
#define HD_ 32
#define GROUPS_ 32
#define EPS_ 1e-5f
// (1/sqrt(32)) * log2(e): QK^T computed directly in log2 domain
#define SCALE2_ 0.25503486f
#define NCH_ 4           // KV chunks
#define CHKV_ 1024       // KV rows per chunk
#define NT_ (CHKV_ / 64) // 64-row KV tiles per chunk

typedef __attribute__((ext_vector_type(2))) float f32x2;
typedef __attribute__((ext_vector_type(4))) float f32x4;
typedef __attribute__((ext_vector_type(8))) short s16x8;
typedef __attribute__((ext_vector_type(2))) unsigned int u32x2;
typedef __attribute__((ext_vector_type(4))) unsigned int u32x4;
typedef unsigned short u16;
typedef unsigned int u32;

static __device__ __forceinline__ u32 cvtpk_bf16(float lo, float hi) {
  u32 r;
  asm("v_cvt_pk_bf16_f32 %0, %1, %2" : "=v"(r) : "v"(lo), "v"(hi));
  return r;
}
// raw v_exp_f32: inputs bounded (|S*log2e| < ~12), no denorm fixup needed.
// (R18/R21 measurements: this sits on the CU-shared trans-unit floor ~26us;
// poly-on-VALU = 48us; mixed split NaN'd (R22, unexplained) -> reverted to
// the known-good pure-trans form.)
static __device__ __forceinline__ float fexp2(float x) {
  float r;
  asm("v_exp_f32 %0, %1" : "=v"(r) : "v"(x));
  return r;
}
// unpack u32 holding 2 bf16 -> 2 f32 (low halfword = first element)
static __device__ __forceinline__ float bflo(u32 w) { return __uint_as_float(w << 16); }
static __device__ __forceinline__ float bfhi(u32 w) { return __uint_as_float(w & 0xffff0000u); }
static __device__ __forceinline__ u16 f2bf16(float f) { return (u16)cvtpk_bf16(f, f); }

// ---------------- GroupNorm -> bf16 xn. One 1024-thread block per (b, group) -
__global__ __launch_bounds__(1024) void k_groupnorm(
    const float* __restrict__ x, const float* __restrict__ gw,
    const float* __restrict__ gb, u16* __restrict__ xn) {
  const int blk = blockIdx.x;            // b*GROUPS + g
  const int tid = threadIdx.x;
  const size_t base = (size_t)blk * (4 * N_);   // contiguous 16384 elems
  const f32x4* x4 = (const f32x4*)(x + base);
  float s = 0.f, ss = 0.f;
  #pragma unroll
  for (int i = tid; i < 4096; i += 1024) {
    f32x4 v = x4[i];
    s  += v.x + v.y + v.z + v.w;
    ss += v.x*v.x + v.y*v.y + v.z*v.z + v.w*v.w;
  }
  for (int off = 32; off; off >>= 1) {
    s  += __shfl_down(s, off);
    ss += __shfl_down(ss, off);
  }
  __shared__ float red[2][16];
  __shared__ float mv[2];
  const int wid = tid >> 6;
  if ((tid & 63) == 0) { red[0][wid] = s; red[1][wid] = ss; }
  __syncthreads();
  if (tid == 0) {
    float S = 0.f, Q = 0.f;
    #pragma unroll
    for (int i = 0; i < 16; ++i) { S += red[0][i]; Q += red[1][i]; }
    float mu  = S * (1.f/16384.f);
    float var = Q * (1.f/16384.f) - mu*mu;
    mv[0] = mu; mv[1] = rsqrtf(var + EPS_);
  }
  __syncthreads();
  const float mu = mv[0], rs = mv[1];
  const int gi = blk & (GROUPS_ - 1);
  u32x2* xn2 = (u32x2*)(xn + base);
  #pragma unroll
  for (int i = tid; i < 4096; i += 1024) {
    const int c = gi*4 + (i >> 10);
    const float a  = gw[c] * rs;
    const float b2 = gb[c] - mu * a;
    f32x4 v = x4[i];
    f32x4 r = v * a + b2;
    u32x2 p = { cvtpk_bf16(r.x, r.y), cvtpk_bf16(r.z, r.w) };
    xn2[i] = p;
  }
}

// ---------------- QKV GEMM -> bf16; K rows written TRANSPOSED to Kt ----------
// Grid (8, 48, B): n-block 512, o-block 8 -> 768 blocks (3/CU, balanced).
__global__ __launch_bounds__(256) void k_gemm_qkv(
    const u16* __restrict__ xn, const float* __restrict__ w,
    const float* __restrict__ bias, u16* __restrict__ qkvb,
    u16* __restrict__ Kt) {
  const int tid = threadIdx.x;
  const int n0 = blockIdx.x * 512 + tid * 2;
  const int o0 = blockIdx.y * 8;
  const int b  = blockIdx.z;
  const u16* xb = xn + (size_t)b * C_ * N_;
  const float* wp = w + (size_t)o0 * C_;
  float ax[8] = {0,0,0,0,0,0,0,0};
  float ay[8] = {0,0,0,0,0,0,0,0};
  #pragma unroll 4
  for (int c = 0; c < C_; ++c) {
    const u32 wv = *(const u32*)(xb + (size_t)c * N_ + n0);
    const float x0 = bflo(wv), x1 = bfhi(wv);
    #pragma unroll
    for (int i = 0; i < 8; ++i) {
      const float wi = wp[(size_t)i * C_ + c];
      ax[i] += x0 * wi;
      ay[i] += x1 * wi;
    }
  }
  #pragma unroll
  for (int i = 0; i < 8; ++i) {
    const float bi = bias[o0 + i];
    ax[i] += bi; ay[i] += bi;
  }
  if (o0 < 128) {            // Q: scale and write rows
    u16* op = qkvb + ((size_t)b * 384 + o0) * N_ + n0;
    #pragma unroll
    for (int i = 0; i < 8; ++i)
      *(u32*)(op + (size_t)i * N_) = cvtpk_bf16(ax[i] * SCALE2_, ay[i] * SCALE2_);
  } else if (o0 < 256) {     // K: transposed into Kt[b][h][m][d]
    const int h  = (o0 - 128) >> 5;
    const int d8 = (o0 - 128) & 31;
    u16* kb = Kt + (size_t)(b * NH_ + h) * N_ * HD_ + d8;
    u32x4 pk0 = { cvtpk_bf16(ax[0], ax[1]), cvtpk_bf16(ax[2], ax[3]),
                  cvtpk_bf16(ax[4], ax[5]), cvtpk_bf16(ax[6], ax[7]) };
    u32x4 pk1 = { cvtpk_bf16(ay[0], ay[1]), cvtpk_bf16(ay[2], ay[3]),
                  cvtpk_bf16(ay[4], ay[5]), cvtpk_bf16(ay[6], ay[7]) };
    *(u32x4*)(kb + (size_t)n0 * HD_)       = pk0;
    *(u32x4*)(kb + (size_t)(n0 + 1) * HD_) = pk1;
  } else {                   // V: write rows
    u16* op = qkvb + ((size_t)b * 384 + o0) * N_ + n0;
    #pragma unroll
    for (int i = 0; i < 8; ++i)
      *(u32*)(op + (size_t)i * N_) = cvtpk_bf16(ax[i], ay[i]);
  }
}

// ---------------- Flash attention: 4 q-tiles/wave, LDS-staged K/V ------------
#define QTILE_STEP(qf, oa0, oa1, oL)                                           \
  {                                                                            \
    f32x4 s0 = __builtin_amdgcn_mfma_f32_16x16x32_bf16(ck0, qf, z, 0, 0, 0);   \
    f32x4 s1 = __builtin_amdgcn_mfma_f32_16x16x32_bf16(ck1, qf, z, 0, 0, 0);   \
    f32x4 s2 = __builtin_amdgcn_mfma_f32_16x16x32_bf16(ck2, qf, z, 0, 0, 0);   \
    f32x4 s3 = __builtin_amdgcn_mfma_f32_16x16x32_bf16(ck3, qf, z, 0, 0, 0);   \
    float p0 = fexp2(s0.x), p1 = fexp2(s0.y), p2 = fexp2(s0.z), p3 = fexp2(s0.w); \
    float p4 = fexp2(s1.x), p5 = fexp2(s1.y), p6 = fexp2(s1.z), p7 = fexp2(s1.w); \
    float p8 = fexp2(s2.x), p9 = fexp2(s2.y), pa_ = fexp2(s2.z), pb_ = fexp2(s2.w); \
    float pc_ = fexp2(s3.x), pd_ = fexp2(s3.y), pe_ = fexp2(s3.z), pf_ = fexp2(s3.w); \
    union { u32x4 u; s16x8 s; } pkA, pkB;                                      \
    pkA.u.x = cvtpk_bf16(p0, p1);   pkA.u.y = cvtpk_bf16(p2, p3);              \
    pkA.u.z = cvtpk_bf16(p4, p5);   pkA.u.w = cvtpk_bf16(p6, p7);              \
    pkB.u.x = cvtpk_bf16(p8, p9);   pkB.u.y = cvtpk_bf16(pa_, pb_);            \
    pkB.u.z = cvtpk_bf16(pc_, pd_); pkB.u.w = cvtpk_bf16(pe_, pf_);            \
    oa0 = __builtin_amdgcn_mfma_f32_16x16x32_bf16(pkA.s, cv0, oa0, 0, 0, 0);   \
    oa1 = __builtin_amdgcn_mfma_f32_16x16x32_bf16(pkA.s, cv1, oa1, 0, 0, 0);   \
    oL  = __builtin_amdgcn_mfma_f32_16x16x32_bf16(pkA.s, onesB, oL, 0, 0, 0);  \
    oa0 = __builtin_amdgcn_mfma_f32_16x16x32_bf16(pkB.s, cv2, oa0, 0, 0, 0);   \
    oa1 = __builtin_amdgcn_mfma_f32_16x16x32_bf16(pkB.s, cv3, oa1, 0, 0, 0);   \
    oL  = __builtin_amdgcn_mfma_f32_16x16x32_bf16(pkB.s, onesB, oL, 0, 0, 0);  \
  }

__global__ __launch_bounds__(256) void k_attn(
    const u16* __restrict__ qkvb, const u16* __restrict__ Kt,
    u16* __restrict__ Opart, float* __restrict__ Lpart) {
  __shared__ u16 Kl[64 * 32];      // [m][d] 4KB, 16B-slot swizzled
  __shared__ u16 Vl[32 * 72];      // [d][m padded] 4.5KB
  const int b = blockIdx.z, h = blockIdx.y;
  const int qt = blockIdx.x & 15, ch = blockIdx.x >> 4;
  const int tid = threadIdx.x;
  const int wid = tid >> 6, lane = tid & 63;
  const int g = lane >> 4, lq = lane & 15;
  const int q0 = qt * 256 + wid * 16;        // tiles at +0, +64, +128, +192
  const int kv0 = ch * CHKV_;

  // Q B-frags (bf16, pre-scaled): one-time scattered u16 loads
  const u16* qb = qkvb + ((size_t)b * 384 + h * HD_) * N_;
  s16x8 qfA, qfB, qfC, qfD;
  #pragma unroll
  for (int j = 0; j < 8; ++j) {
    const u16* qr = qb + (size_t)(8*g + j) * N_ + q0 + lq;
    qfA[j] = (short)qr[0];
    qfB[j] = (short)qr[64];
    qfC[j] = (short)qr[128];
    qfD[j] = (short)qr[192];
  }

  const u16* ktb = Kt + (size_t)(b * NH_ + h) * N_ * HD_;            // [m][d]
  const u16* vbb = qkvb + ((size_t)b * 384 + 256 + h * HD_) * N_;    // [d][m]
  const int pi = ((lq >> 2) << 3) + (lq & 3);   // A-row -> K row permutation

  // staging (coalesced): K = one s16x8/thread, V = one s16x8/thread
  const u16* kst = ktb + (size_t)kv0 * HD_ + tid * 8;        // + tt*64*HD_
  const int vrow = tid >> 3;            // 0..31 (d)
  const int vcol = (tid & 7) * 8;       // 0..56 (m)
  const u16* vst = vbb + (size_t)vrow * N_ + kv0 + vcol;     // + tt*64
  u16* kdst = Kl + ((tid * 8) ^ (((tid >> 5) & 3) * 8));     // swizzled slot
  u16* vdst = Vl + vrow * 72 + vcol;

  // fragment LDS addresses (elements); K slots swizzled by x=(pi>>3)&3
  const int xsw  = (pi >> 3) & 3;
  const int slot = 8 * (g ^ xsw);
  const int ka0 = (pi)      * 32 + slot;
  const int ka1 = (pi + 4)  * 32 + slot;
  const int ka2 = (pi + 32) * 32 + slot;
  const int ka3 = (pi + 36) * 32 + slot;
  const int va0 = lq * 72 + 8*g;
  const int va1 = (lq + 16) * 72 + 8*g;

  const short one_bf = (short)0x3F80;   // bf16 1.0
  const s16x8 onesB = {one_bf, one_bf, one_bf, one_bf,
                       one_bf, one_bf, one_bf, one_bf};

  f32x4 oa0A = {0.f,0.f,0.f,0.f}, oa1A = oa0A, oLA = oa0A;
  f32x4 oa0B = oa0A, oa1B = oa0A, oLB = oa0A;
  f32x4 oa0C = oa0A, oa1C = oa0A, oLC = oa0A;
  f32x4 oa0D = oa0A, oa1D = oa0A, oLD = oa0A;

  // prologue: stage tile 0
  {
    s16x8 kr = *(const s16x8*)(kst);
    s16x8 vr = *(const s16x8*)(vst);
    *(s16x8*)(kdst) = kr;
    *(s16x8*)(vdst) = vr;
  }
  __syncthreads();

  for (int tt = 0; tt < NT_; ++tt) {
    // issue next-tile loads early (clamped on last iter; rewrite is harmless)
    const int tn = (tt + 1 < NT_) ? (tt + 1) : (NT_ - 1);
    s16x8 kr = *(const s16x8*)(kst + (size_t)tn * 64 * HD_);
    s16x8 vr = *(const s16x8*)(vst + (size_t)tn * 64);

    // fragments from LDS (shared by all four q-tiles)
    const s16x8 ck0 = *(const s16x8*)(Kl + ka0);
    const s16x8 ck1 = *(const s16x8*)(Kl + ka1);
    const s16x8 ck2 = *(const s16x8*)(Kl + ka2);
    const s16x8 ck3 = *(const s16x8*)(Kl + ka3);
    const s16x8 cv0 = *(const s16x8*)(Vl + va0);
    const s16x8 cv1 = *(const s16x8*)(Vl + va1);
    const s16x8 cv2 = *(const s16x8*)(Vl + va0 + 32);
    const s16x8 cv3 = *(const s16x8*)(Vl + va1 + 32);

    const f32x4 z = {0.f,0.f,0.f,0.f};
    QTILE_STEP(qfA, oa0A, oa1A, oLA)
    QTILE_STEP(qfB, oa0B, oa1B, oLB)
    QTILE_STEP(qfC, oa0C, oa1C, oLC)
    QTILE_STEP(qfD, oa0D, oa1D, oLD)

    __syncthreads();                 // all reads of Kl/Vl done
    *(s16x8*)(kdst) = kr;            // overwrite with next tile
    *(s16x8*)(vdst) = vr;
    __syncthreads();                 // next tile visible
  }

  // partial store (bf16): Opart[ch][b][h][q][d], Lpart[ch][b][h][q]
  const int bh = b * NH_ + h;
  u16* opb = Opart + ((size_t)ch * (B_ * NH_) + bh) * ((size_t)N_ * HD_);
  #pragma unroll
  for (int r = 0; r < 4; ++r) {
    const int qrow = q0 + g*4 + r;
    opb[(size_t)qrow * HD_ + lq]              = f2bf16(oa0A[r]);
    opb[(size_t)qrow * HD_ + lq + 16]         = f2bf16(oa1A[r]);
    opb[(size_t)(qrow + 64) * HD_ + lq]       = f2bf16(oa0B[r]);
    opb[(size_t)(qrow + 64) * HD_ + lq + 16]  = f2bf16(oa1B[r]);
    opb[(size_t)(qrow + 128) * HD_ + lq]      = f2bf16(oa0C[r]);
    opb[(size_t)(qrow + 128) * HD_ + lq + 16] = f2bf16(oa1C[r]);
    opb[(size_t)(qrow + 192) * HD_ + lq]      = f2bf16(oa0D[r]);
    opb[(size_t)(qrow + 192) * HD_ + lq + 16] = f2bf16(oa1D[r]);
  }
  if (lq == 0) {
    float* lp = Lpart + ((size_t)ch * (B_ * NH_) + bh) * N_ + q0 + g*4;
    lp[0]   = oLA[0]; lp[1]   = oLA[1]; lp[2]   = oLA[2]; lp[3]   = oLA[3];
    lp[64]  = oLB[0]; lp[65]  = oLB[1]; lp[66]  = oLB[2]; lp[67]  = oLB[3];
    lp[128] = oLC[0]; lp[129] = oLC[1]; lp[130] = oLC[2]; lp[131] = oLC[3];
    lp[192] = oLD[0]; lp[193] = oLD[1]; lp[194] = oLD[2]; lp[195] = oLD[3];
  }
}

// ---------------- Fused combine + out GEMM + bias + residual -----------------
// Grid (32, 4, B): block = [128 n] x [32 o].
__global__ __launch_bounds__(256) void k_out(
    const u16* __restrict__ Opart, const float* __restrict__ Lpart,
    const float* __restrict__ w, const float* __restrict__ bias,
    const float* __restrict__ x, float* __restrict__ y) {
  __shared__ u16 Ot[128][136];     // [c][n] bf16, +8 pad
  __shared__ float linv[NH_][128];
  const int t = threadIdx.x;
  const int n0 = blockIdx.x * 128;
  const int o0 = blockIdx.y * 32;
  const int b  = blockIdx.z;

  // per-head denominators for this n-range
  if (t < 128) {
    #pragma unroll
    for (int h = 0; h < NH_; ++h) {
      float s = 0.f;
      #pragma unroll
      for (int c = 0; c < NCH_; ++c)
        s += Lpart[((size_t)c * (B_ * NH_) + b * NH_ + h) * N_ + n0 + t];
      linv[h][t] = 1.0f / s;
    }
  }
  __syncthreads();

  // stage Ot[c=32h+d][n] = (sum_ch Opart[ch][bh][n0+n][d]) * linv[h][n]
  {
    const int dd = (t & 7) * 4;           // 0..28
    const int nb = t >> 3;                // 0..31
    #pragma unroll
    for (int h = 0; h < NH_; ++h) {
      const u16* ob = Opart + (size_t)(b * NH_ + h) * ((size_t)N_ * HD_)
                    + (size_t)n0 * HD_ + dd;
      #pragma unroll
      for (int p = 0; p < 4; ++p) {
        const int nn = p * 32 + nb;
        f32x4 a = {0.f,0.f,0.f,0.f};
        #pragma unroll
        for (int c = 0; c < NCH_; ++c) {
          const u32x2 ov = *(const u32x2*)(ob
              + (size_t)c * ((size_t)B_ * NH_ * N_ * HD_) + (size_t)nn * HD_);
          a.x += bflo(ov.x); a.y += bfhi(ov.x);
          a.z += bflo(ov.y); a.w += bfhi(ov.y);
        }
        const float iv = linv[h][nn];
        a *= iv;
        Ot[32*h + dd + 0][nn] = f2bf16(a.x);
        Ot[32*h + dd + 1][nn] = f2bf16(a.y);
        Ot[32*h + dd + 2][nn] = f2bf16(a.z);
        Ot[32*h + dd + 3][nn] = f2bf16(a.w);
      }
    }
  }
  __syncthreads();

  // GEMM: thread -> 4 o-rows x 4 n-cols
  const int n4  = (t & 31) * 4;             // 0..124
  const int orow = o0 + (t >> 5) * 4;       // 4 rows
  const float* wp = w + (size_t)orow * C_;
  f32x4 acc0 = {0.f,0.f,0.f,0.f}, acc1 = acc0, acc2 = acc0, acc3 = acc0;
  #pragma unroll 4
  for (int c = 0; c < C_; ++c) {
    const u32x2 ov = *(const u32x2*)(&Ot[c][n4]);
    const f32x4 xv = { bflo(ov.x), bfhi(ov.x), bflo(ov.y), bfhi(ov.y) };
    acc0 += xv * wp[c];
    acc1 += xv * wp[C_ + c];
    acc2 += xv * wp[2*C_ + c];
    acc3 += xv * wp[3*C_ + c];
  }
  const size_t yo = ((size_t)b * C_ + orow) * N_ + n0 + n4;
  const f32x4 xr0 = *(const f32x4*)(x + yo);
  const f32x4 xr1 = *(const f32x4*)(x + yo + N_);
  const f32x4 xr2 = *(const f32x4*)(x + yo + 2*N_);
  const f32x4 xr3 = *(const f32x4*)(x + yo + 3*N_);
  *(f32x4*)(y + yo)        = acc0 + bias[orow]     + xr0;
  *(f32x4*)(y + yo + N_)   = acc1 + bias[orow + 1] + xr1;
  *(f32x4*)(y + yo + 2*N_) = acc2 + bias[orow + 2] + xr2;
  *(f32x4*)(y + yo + 3*N_) = acc3 + bias[orow + 3] + xr3;
}

extern "C" void kernel_launch(void* const* d_in, const int* in_sizes, int n_in,
                              void* d_out, int out_size, void* d_ws, size_t ws_size,
                              hipStream_t stream) {
  const float* x     = (const float*)d_in[0];
  const float* gn_w  = (const float*)d_in[1];
  const float* gn_b  = (const float*)d_in[2];
  const float* qkv_w = (const float*)d_in[3];
  const float* qkv_b = (const float*)d_in[4];
  const float* out_w = (const float*)d_in[5];
  const float* out_b = (const float*)d_in[6];
  float* y = (float*)d_out;

  // ws layout (float offsets):
  //   xn    bf16: [0, 524288)            2 MB
  //   qkvb  bf16: [524288, 2097152)      6 MB  (Q scaled | unused | V)
  //   Kt    bf16: [2097152, 2621440)     2 MB
  //   Opart bf16: [2621440, 4718592)     8 MB  (4 chunks x [b][h][4096][32])
  //   Lpart f32 : [4718592, 4849664)   0.5 MB
  float* ws  = (float*)d_ws;
  u16*   xn   = (u16*)ws;
  u16*   qkvb = (u16*)(ws + 524288);
  u16*   Kt   = (u16*)(ws + 2097152);
  u16*   Opart = (u16*)(ws + 2621440);
  float* Lpart = ws + 4718592;

  k_groupnorm<<<dim3(B_ * GROUPS_), 1024, 0, stream>>>(x, gn_w, gn_b, xn);
  k_gemm_qkv <<<dim3(8, 48, B_),    256, 0, stream>>>(xn, qkv_w, qkv_b, qkvb, Kt);
  k_attn     <<<dim3(16 * NCH_, NH_, B_), 256, 0, stream>>>(qkvb, Kt, Opart, Lpart);
  k_out      <<<dim3(32, 4, B_),    256, 0, stream>>>(Opart, Lpart, out_w, out_b, x, y);
}